// Round 1
// baseline (5638.338 us; speedup 1.0000x reference)
//
#include <hip/hip_runtime.h>

#define M_TOK 32768
#define DIN   512
#define DEMB  1024
#define KC    4096

#define IDX_OFF ((size_t)M_TOK * DIN)                 // 16777216
#define Q_OFF   (IDX_OFF + M_TOK)                     // 16809984
#define AUX_OFF (Q_OFF + (size_t)M_TOK * DEMB)        // 50364416

// ---------------- block reduction (256 threads = 4 waves) ----------------
__device__ inline float block_reduce_sum_256(float v) {
#pragma unroll
    for (int off = 32; off > 0; off >>= 1) v += __shfl_down(v, off);
    __shared__ float smem[4];
    const int lane = threadIdx.x & 63;
    const int w = threadIdx.x >> 6;
    if (lane == 0) smem[w] = v;
    __syncthreads();
    return smem[0] + smem[1] + smem[2] + smem[3];
}

// ---------------- codebook squared norms; also zero the aux-loss slot ----
__global__ __launch_bounds__(256) void cnorm_kernel(const float* __restrict__ cb,
                                                    float* __restrict__ cnorm,
                                                    float* __restrict__ aux) {
    if (blockIdx.x == 0 && threadIdx.x == 0) *aux = 0.0f;
    const float* row = cb + (size_t)blockIdx.x * DEMB;
    const float4 v = *reinterpret_cast<const float4*>(row + threadIdx.x * 4);
    float s = v.x * v.x + v.y * v.y + v.z * v.z + v.w * v.w;
    s = block_reduce_sum_256(s);
    if (threadIdx.x == 0) cnorm[blockIdx.x] = s;
}

// ---------------- fp32 NT GEMM: C[m,n] = dot(A[m,:], B[n,:]) + bias[n] ----
// BM=BN=64, BK=32, 256 threads (16x16), 4x4 microtile.
// GATHER: A row m is codebook[gidx[m]].
template <bool GATHER>
__global__ __launch_bounds__(256) void gemm_nt64(const float* __restrict__ A,
                                                 const float* __restrict__ Bm,
                                                 const float* __restrict__ bias,
                                                 float* __restrict__ C,
                                                 const int* __restrict__ gidx,
                                                 int K, int N) {
    __shared__ float As[32][68];   // [k][m], pad 68 -> 16B-aligned rows
    __shared__ float Bs[32][68];   // [k][n]
    const int tid = threadIdx.x;
    const int tx = tid & 15, ty = tid >> 4;
    const int m0 = blockIdx.y * 64, n0 = blockIdx.x * 64;
    const int lr = tid >> 3;        // 0..31
    const int kc = (tid & 7) * 4;   // 0,4,...,28

    const float* pa0;
    const float* pa1;
    if (GATHER) {
        pa0 = A + (size_t)gidx[m0 + lr] * K + kc;
        pa1 = A + (size_t)gidx[m0 + lr + 32] * K + kc;
    } else {
        pa0 = A + (size_t)(m0 + lr) * K + kc;
        pa1 = A + (size_t)(m0 + lr + 32) * K + kc;
    }
    const float* pb0 = Bm + (size_t)(n0 + lr) * K + kc;
    const float* pb1 = Bm + (size_t)(n0 + lr + 32) * K + kc;

    float acc[4][4] = {};
    for (int k0 = 0; k0 < K; k0 += 32) {
        const float4 a0 = *reinterpret_cast<const float4*>(pa0 + k0);
        const float4 a1 = *reinterpret_cast<const float4*>(pa1 + k0);
        const float4 b0 = *reinterpret_cast<const float4*>(pb0 + k0);
        const float4 b1 = *reinterpret_cast<const float4*>(pb1 + k0);
        __syncthreads();
        As[kc + 0][lr] = a0.x; As[kc + 1][lr] = a0.y; As[kc + 2][lr] = a0.z; As[kc + 3][lr] = a0.w;
        As[kc + 0][lr + 32] = a1.x; As[kc + 1][lr + 32] = a1.y; As[kc + 2][lr + 32] = a1.z; As[kc + 3][lr + 32] = a1.w;
        Bs[kc + 0][lr] = b0.x; Bs[kc + 1][lr] = b0.y; Bs[kc + 2][lr] = b0.z; Bs[kc + 3][lr] = b0.w;
        Bs[kc + 0][lr + 32] = b1.x; Bs[kc + 1][lr + 32] = b1.y; Bs[kc + 2][lr + 32] = b1.z; Bs[kc + 3][lr + 32] = b1.w;
        __syncthreads();
#pragma unroll
        for (int kk = 0; kk < 32; ++kk) {
            const float4 av = *reinterpret_cast<const float4*>(&As[kk][ty * 4]);
            const float4 bv = *reinterpret_cast<const float4*>(&Bs[kk][tx * 4]);
            const float a[4] = {av.x, av.y, av.z, av.w};
            const float b[4] = {bv.x, bv.y, bv.z, bv.w};
#pragma unroll
            for (int i = 0; i < 4; ++i)
#pragma unroll
                for (int j = 0; j < 4; ++j) acc[i][j] = fmaf(a[i], b[j], acc[i][j]);
        }
    }
    const float4 bb = *reinterpret_cast<const float4*>(bias + n0 + tx * 4);
    const float badd[4] = {bb.x, bb.y, bb.z, bb.w};
#pragma unroll
    for (int i = 0; i < 4; ++i) {
        float4 o;
        o.x = acc[i][0] + badd[0];
        o.y = acc[i][1] + badd[1];
        o.z = acc[i][2] + badd[2];
        o.w = acc[i][3] + badd[3];
        *reinterpret_cast<float4*>(C + (size_t)(m0 + ty * 4 + i) * N + n0 + tx * 4) = o;
    }
}

// ---------------- distance argmin over one slab of 1024 codes ------------
// dist_rel(t,k) = ||c_k||^2 - 2 * dot(z_t, c_k)   (||z||^2 dropped: constant per t)
__global__ __launch_bounds__(256) void argmin_part(const float* __restrict__ z,
                                                   const float* __restrict__ cb,
                                                   const float* __restrict__ cnorm,
                                                   float* __restrict__ vpart,
                                                   int* __restrict__ ipart) {
    __shared__ float As[32][68];
    __shared__ float Bs[32][68];
    const int tid = threadIdx.x;
    const int tx = tid & 15, ty = tid >> 4;
    const int m0 = blockIdx.x * 64;
    const int slab = blockIdx.y;  // 0..3
    const int lr = tid >> 3;
    const int kc = (tid & 7) * 4;

    const float* pa0 = z + (size_t)(m0 + lr) * DEMB + kc;
    const float* pa1 = pa0 + (size_t)32 * DEMB;

    float vmin[4];
    int imin[4];
#pragma unroll
    for (int i = 0; i < 4; ++i) { vmin[i] = INFINITY; imin[i] = 0x7fffffff; }

    for (int nb = 0; nb < 16; ++nb) {
        const int n0 = slab * 1024 + nb * 64;
        const float* pb0 = cb + (size_t)(n0 + lr) * DEMB + kc;
        const float* pb1 = pb0 + (size_t)32 * DEMB;
        float acc[4][4] = {};
        for (int k0 = 0; k0 < DEMB; k0 += 32) {
            const float4 a0 = *reinterpret_cast<const float4*>(pa0 + k0);
            const float4 a1 = *reinterpret_cast<const float4*>(pa1 + k0);
            const float4 b0 = *reinterpret_cast<const float4*>(pb0 + k0);
            const float4 b1 = *reinterpret_cast<const float4*>(pb1 + k0);
            __syncthreads();
            As[kc + 0][lr] = a0.x; As[kc + 1][lr] = a0.y; As[kc + 2][lr] = a0.z; As[kc + 3][lr] = a0.w;
            As[kc + 0][lr + 32] = a1.x; As[kc + 1][lr + 32] = a1.y; As[kc + 2][lr + 32] = a1.z; As[kc + 3][lr + 32] = a1.w;
            Bs[kc + 0][lr] = b0.x; Bs[kc + 1][lr] = b0.y; Bs[kc + 2][lr] = b0.z; Bs[kc + 3][lr] = b0.w;
            Bs[kc + 0][lr + 32] = b1.x; Bs[kc + 1][lr + 32] = b1.y; Bs[kc + 2][lr + 32] = b1.z; Bs[kc + 3][lr + 32] = b1.w;
            __syncthreads();
#pragma unroll
            for (int kk = 0; kk < 32; ++kk) {
                const float4 av = *reinterpret_cast<const float4*>(&As[kk][ty * 4]);
                const float4 bv = *reinterpret_cast<const float4*>(&Bs[kk][tx * 4]);
                const float a[4] = {av.x, av.y, av.z, av.w};
                const float b[4] = {bv.x, bv.y, bv.z, bv.w};
#pragma unroll
                for (int i = 0; i < 4; ++i)
#pragma unroll
                    for (int j = 0; j < 4; ++j) acc[i][j] = fmaf(a[i], b[j], acc[i][j]);
            }
        }
        const float4 cn4 = *reinterpret_cast<const float4*>(cnorm + n0 + tx * 4);
        const float cn[4] = {cn4.x, cn4.y, cn4.z, cn4.w};
#pragma unroll
        for (int j = 0; j < 4; ++j) {
            const int code = n0 + tx * 4 + j;
#pragma unroll
            for (int i = 0; i < 4; ++i) {
                const float d = cn[j] - 2.0f * acc[i][j];
                if (d < vmin[i]) { vmin[i] = d; imin[i] = code; }  // codes ascend -> strict < keeps first
            }
        }
    }
    // butterfly min-reduce across the 16 tx lanes (same-ty groups within the wave)
#pragma unroll
    for (int off = 1; off < 16; off <<= 1) {
#pragma unroll
        for (int i = 0; i < 4; ++i) {
            const float v2 = __shfl_xor(vmin[i], off);
            const int i2 = __shfl_xor(imin[i], off);
            if (v2 < vmin[i] || (v2 == vmin[i] && i2 < imin[i])) { vmin[i] = v2; imin[i] = i2; }
        }
    }
    if (tx == 0) {
#pragma unroll
        for (int i = 0; i < 4; ++i) {
            const int t = m0 + ty * 4 + i;
            vpart[(size_t)slab * M_TOK + t] = vmin[i];
            ipart[(size_t)slab * M_TOK + t] = imin[i];
        }
    }
}

// ---------------- merge 4 slabs -> final index (first-min tie-break) -----
__global__ __launch_bounds__(256) void argmin_merge(const float* __restrict__ vp,
                                                    const int* __restrict__ ip,
                                                    float* __restrict__ idx_f,
                                                    int* __restrict__ idx_i) {
    const int t = blockIdx.x * 256 + threadIdx.x;
    float v = vp[t];
    int ix = ip[t];
#pragma unroll
    for (int s = 1; s < 4; ++s) {
        const float v2 = vp[(size_t)s * M_TOK + t];
        const int i2 = ip[(size_t)s * M_TOK + t];
        if (v2 < v || (v2 == v && i2 < ix)) { v = v2; ix = i2; }
    }
    idx_f[t] = (float)ix;
    idx_i[t] = ix;
}

// ---------------- gather q, in-place z->q, aux loss ----------------------
__global__ __launch_bounds__(256) void quant_aux(const float* __restrict__ cb,
                                                 const int* __restrict__ idx,
                                                 float* __restrict__ zq,
                                                 float* __restrict__ aux) {
    const int t = blockIdx.x;
    const float* c = cb + (size_t)idx[t] * DEMB;
    float* p = zq + (size_t)t * DEMB;
    const int i = threadIdx.x * 4;
    const float4 cv = *reinterpret_cast<const float4*>(c + i);
    const float4 zv = *reinterpret_cast<const float4*>(p + i);
    const float dx = cv.x - zv.x, dy = cv.y - zv.y, dz = cv.z - zv.z, dw = cv.w - zv.w;
    float s = dx * dx + dy * dy + dz * dz + dw * dw;
    *reinterpret_cast<float4*>(p + i) = cv;
    s = block_reduce_sum_256(s);
    if (threadIdx.x == 0) atomicAdd(aux, s * (1.0f / 33554432.0f));
}

extern "C" void kernel_launch(void* const* d_in, const int* in_sizes, int n_in,
                              void* d_out, int out_size, void* d_ws, size_t ws_size,
                              hipStream_t stream) {
    const float* x = (const float*)d_in[0];
    const float* w_in = (const float*)d_in[1];
    const float* b_in = (const float*)d_in[2];
    const float* w_out = (const float*)d_in[3];
    const float* b_out = (const float*)d_in[4];
    const float* cb = (const float*)d_in[5];

    float* out = (float*)d_out;              // [32768, 512]
    float* idx_f = out + IDX_OFF;            // [32768] as float
    float* zq = out + Q_OFF;                 // [32768, 1024]: holds z, then quantized
    float* aux = out + AUX_OFF;              // scalar

    float* cnorm = (float*)d_ws;                                         // 4096 f
    int* idx_i = (int*)((char*)d_ws + 4096 * 4);                         // 32768 i
    float* vpart = (float*)((char*)d_ws + 4096 * 4 + M_TOK * 4);         // 4*32768 f
    int* ipart = (int*)((char*)d_ws + 4096 * 4 + M_TOK * 4 + 4 * M_TOK * 4);  // 4*32768 i

    // 1) codebook norms (+ zero aux)
    cnorm_kernel<<<KC, 256, 0, stream>>>(cb, cnorm, aux);
    // 2) z = x @ w_in^T + b_in  -> written into the quantized output slab
    gemm_nt64<false><<<dim3(DEMB / 64, M_TOK / 64), 256, 0, stream>>>(x, w_in, b_in, zq, nullptr, DIN, DEMB);
    // 3) argmin over codebook (4 slabs of 1024 codes)
    argmin_part<<<dim3(M_TOK / 64, 4), 256, 0, stream>>>(zq, cb, cnorm, vpart, ipart);
    argmin_merge<<<M_TOK / 256, 256, 0, stream>>>(vpart, ipart, idx_f, idx_i);
    // 4) quantized = codebook[idx] (in place over z), aux = mean((q-z)^2)
    quant_aux<<<M_TOK, 256, 0, stream>>>(cb, idx_i, zq, aux);
    // 5) out = q @ w_out^T + b_out (gathered A)
    gemm_nt64<true><<<dim3(DIN / 64, M_TOK / 64), 256, 0, stream>>>(cb, w_out, b_out, out, idx_i, DEMB, DIN);
}

// Round 2
// 1939.790 us; speedup vs baseline: 2.9067x; 2.9067x over previous
//
#include <hip/hip_runtime.h>

#define M_TOK 32768
#define DIN   512
#define DEMB  1024
#define KC    4096

#define IDX_OFF ((size_t)M_TOK * DIN)                 // 16777216 floats
#define Q_OFF   (IDX_OFF + M_TOK)                     // 16809984
#define AUX_OFF (Q_OFF + (size_t)M_TOK * DEMB)        // 50364416

typedef _Float16 f16x8 __attribute__((ext_vector_type(8)));
typedef float f32x4 __attribute__((ext_vector_type(4)));

__device__ inline void gload16(const void* g, void* s) {
    __builtin_amdgcn_global_load_lds((const __attribute__((address_space(1))) void*)g,
                                     (__attribute__((address_space(3))) void*)s, 16, 0, 0);
}

// ---------------- block reduction (256 threads = 4 waves) ----------------
__device__ inline float block_reduce_sum_256(float v) {
#pragma unroll
    for (int off = 32; off > 0; off >>= 1) v += __shfl_down(v, off);
    __shared__ float smem[4];
    const int lane = threadIdx.x & 63;
    const int w = threadIdx.x >> 6;
    if (lane == 0) smem[w] = v;
    __syncthreads();
    return smem[0] + smem[1] + smem[2] + smem[3];
}

// ---------------- codebook squared norms; also zero the aux-loss slot ----
__global__ __launch_bounds__(256) void cnorm_kernel(const float* __restrict__ cb,
                                                    float* __restrict__ cnorm,
                                                    float* __restrict__ aux) {
    if (blockIdx.x == 0 && threadIdx.x == 0) *aux = 0.0f;
    const float* row = cb + (size_t)blockIdx.x * DEMB;
    const float4 v = *reinterpret_cast<const float4*>(row + threadIdx.x * 4);
    float s = v.x * v.x + v.y * v.y + v.z * v.z + v.w * v.w;
    s = block_reduce_sum_256(s);
    if (threadIdx.x == 0) cnorm[blockIdx.x] = s;
}

// ---------------- fp32 NT GEMM: C[m,n] = dot(A[m,:], B[n,:]) + bias[n] ----
template <bool GATHER>
__global__ __launch_bounds__(256) void gemm_nt64(const float* __restrict__ A,
                                                 const float* __restrict__ Bm,
                                                 const float* __restrict__ bias,
                                                 float* __restrict__ C,
                                                 const int* __restrict__ gidx,
                                                 int K, int N) {
    __shared__ float As[32][68];
    __shared__ float Bs[32][68];
    const int tid = threadIdx.x;
    const int tx = tid & 15, ty = tid >> 4;
    const int m0 = blockIdx.y * 64, n0 = blockIdx.x * 64;
    const int lr = tid >> 3;
    const int kc = (tid & 7) * 4;

    const float* pa0;
    const float* pa1;
    if (GATHER) {
        pa0 = A + (size_t)gidx[m0 + lr] * K + kc;
        pa1 = A + (size_t)gidx[m0 + lr + 32] * K + kc;
    } else {
        pa0 = A + (size_t)(m0 + lr) * K + kc;
        pa1 = A + (size_t)(m0 + lr + 32) * K + kc;
    }
    const float* pb0 = Bm + (size_t)(n0 + lr) * K + kc;
    const float* pb1 = Bm + (size_t)(n0 + lr + 32) * K + kc;

    float acc[4][4] = {};
    for (int k0 = 0; k0 < K; k0 += 32) {
        const float4 a0 = *reinterpret_cast<const float4*>(pa0 + k0);
        const float4 a1 = *reinterpret_cast<const float4*>(pa1 + k0);
        const float4 b0 = *reinterpret_cast<const float4*>(pb0 + k0);
        const float4 b1 = *reinterpret_cast<const float4*>(pb1 + k0);
        __syncthreads();
        As[kc + 0][lr] = a0.x; As[kc + 1][lr] = a0.y; As[kc + 2][lr] = a0.z; As[kc + 3][lr] = a0.w;
        As[kc + 0][lr + 32] = a1.x; As[kc + 1][lr + 32] = a1.y; As[kc + 2][lr + 32] = a1.z; As[kc + 3][lr + 32] = a1.w;
        Bs[kc + 0][lr] = b0.x; Bs[kc + 1][lr] = b0.y; Bs[kc + 2][lr] = b0.z; Bs[kc + 3][lr] = b0.w;
        Bs[kc + 0][lr + 32] = b1.x; Bs[kc + 1][lr + 32] = b1.y; Bs[kc + 2][lr + 32] = b1.z; Bs[kc + 3][lr + 32] = b1.w;
        __syncthreads();
#pragma unroll
        for (int kk = 0; kk < 32; ++kk) {
            const float4 av = *reinterpret_cast<const float4*>(&As[kk][ty * 4]);
            const float4 bv = *reinterpret_cast<const float4*>(&Bs[kk][tx * 4]);
            const float a[4] = {av.x, av.y, av.z, av.w};
            const float b[4] = {bv.x, bv.y, bv.z, bv.w};
#pragma unroll
            for (int i = 0; i < 4; ++i)
#pragma unroll
                for (int j = 0; j < 4; ++j) acc[i][j] = fmaf(a[i], b[j], acc[i][j]);
        }
    }
    const float4 bb = *reinterpret_cast<const float4*>(bias + n0 + tx * 4);
    const float badd[4] = {bb.x, bb.y, bb.z, bb.w};
#pragma unroll
    for (int i = 0; i < 4; ++i) {
        float4 o;
        o.x = acc[i][0] + badd[0];
        o.y = acc[i][1] + badd[1];
        o.z = acc[i][2] + badd[2];
        o.w = acc[i][3] + badd[3];
        *reinterpret_cast<float4*>(C + (size_t)(m0 + ty * 4 + i) * N + n0 + tx * 4) = o;
    }
}

// ---------------- fp32 -> fp16 conversion (z and codebook) ---------------
__global__ __launch_bounds__(256) void to_f16(const float* __restrict__ z,
                                              const float* __restrict__ cb,
                                              _Float16* __restrict__ zf,
                                              _Float16* __restrict__ cbf) {
    const size_t NZ = (size_t)M_TOK * DEMB / 8;
    const size_t NT = NZ + (size_t)KC * DEMB / 8;
    for (size_t i = (size_t)blockIdx.x * 256 + threadIdx.x; i < NT; i += (size_t)gridDim.x * 256) {
        const float* src;
        _Float16* dst;
        size_t j;
        if (i < NZ) { src = z; dst = zf; j = i; }
        else        { src = cb; dst = cbf; j = i - NZ; }
        const float4 a = reinterpret_cast<const float4*>(src)[j * 2];
        const float4 b = reinterpret_cast<const float4*>(src)[j * 2 + 1];
        f16x8 h;
        h[0] = (_Float16)a.x; h[1] = (_Float16)a.y; h[2] = (_Float16)a.z; h[3] = (_Float16)a.w;
        h[4] = (_Float16)b.x; h[5] = (_Float16)b.y; h[6] = (_Float16)b.z; h[7] = (_Float16)b.w;
        reinterpret_cast<f16x8*>(dst)[j] = h;
    }
}

// ---------------- fp16 MFMA distance GEMM + per-group top-2 --------------
// 128x128 tile, 4 waves 2x2, mfma_f32_16x16x32_f16, BK=64, global_load_lds
// staging with XOR-swizzled source (linear LDS dest, swizzled ds_read).
// Approx dist = cnorm[c] - 2*dot(z_t, c)  (||z||^2 constant per token).
// Output: top-2 (value,index) per token per 512-col group (8 groups).
__global__ __launch_bounds__(256, 2) void dist_topk(const _Float16* __restrict__ zf,
                                                    const _Float16* __restrict__ cbf,
                                                    const float* __restrict__ cnorm,
                                                    float* __restrict__ pv,
                                                    int* __restrict__ pi) {
    __shared__ _Float16 lds[16384];  // A tile [128][64] at 0, B tile at 8192 (f16 units)
    const int tid = threadIdx.x;
    const int w = tid >> 6, l = tid & 63;
    const int wm = w >> 1, wn = w & 1;
    const int lg = l >> 4, lc = l & 15;
    const int m0 = blockIdx.x * 128;
    const int c0 = blockIdx.y * 1024;

    const int srow = l >> 3;                 // 0..7
    const int schunk = (l & 7) ^ srow;       // pre-swizzled source chunk

    f32x4 acc[4][4];
    float sv[16][2];
    int si[16][2];
#pragma unroll
    for (int r = 0; r < 16; ++r) { sv[r][0] = 3.4e38f; sv[r][1] = 3.4e38f; si[r][0] = 0; si[r][1] = 0; }

    for (int nt = 0; nt < 8; ++nt) {
        const int n0 = c0 + nt * 128;
#pragma unroll
        for (int m = 0; m < 4; ++m)
#pragma unroll
            for (int n = 0; n < 4; ++n) acc[m][n] = (f32x4){0.f, 0.f, 0.f, 0.f};

        for (int kt = 0; kt < 16; ++kt) {
            __syncthreads();  // previous compute done before overwrite
#pragma unroll
            for (int i = 0; i < 4; ++i) {
                const int row = (i * 4 + w) * 8 + srow;
                const _Float16* gA = zf + (((size_t)(m0 + row)) << 10) + kt * 64 + schunk * 8;
                const _Float16* gB = cbf + (((size_t)(n0 + row)) << 10) + kt * 64 + schunk * 8;
                _Float16* sA = lds + row * 64 + (l & 7) * 8;          // linear: base + lane*16B
                _Float16* sB = lds + 8192 + row * 64 + (l & 7) * 8;
                gload16(gA, sA);
                gload16(gB, sB);
            }
            __syncthreads();  // drains vmcnt(0)
#pragma unroll
            for (int kk = 0; kk < 2; ++kk) {
                f16x8 af[4], bfr[4];
#pragma unroll
                for (int m = 0; m < 4; ++m) {
                    const int r = wm * 64 + m * 16 + lc;
                    const int ch = (kk * 4 + lg) ^ (r & 7);
                    af[m] = *reinterpret_cast<const f16x8*>(lds + r * 64 + ch * 8);
                }
#pragma unroll
                for (int n = 0; n < 4; ++n) {
                    const int r = wn * 64 + n * 16 + lc;
                    const int ch = (kk * 4 + lg) ^ (r & 7);
                    bfr[n] = *reinterpret_cast<const f16x8*>(lds + 8192 + r * 64 + ch * 8);
                }
#pragma unroll
                for (int m = 0; m < 4; ++m)
#pragma unroll
                    for (int n = 0; n < 4; ++n)
                        acc[m][n] = __builtin_amdgcn_mfma_f32_16x16x32_f16(af[m], bfr[n], acc[m][n], 0, 0, 0);
            }
        }
        // insert this N-tile's distances into per-lane top-2 per owned row
#pragma unroll
        for (int n = 0; n < 4; ++n) {
            const int col = n0 + wn * 64 + n * 16 + lc;
            const float cn = cnorm[col];
#pragma unroll
            for (int m = 0; m < 4; ++m) {
#pragma unroll
                for (int reg = 0; reg < 4; ++reg) {
                    const float d = cn - 2.0f * acc[m][n][reg];
                    const int r = m * 4 + reg;
                    if (d < sv[r][0]) {
                        sv[r][1] = sv[r][0]; si[r][1] = si[r][0];
                        sv[r][0] = d;        si[r][0] = col;
                    } else if (d < sv[r][1]) {
                        sv[r][1] = d; si[r][1] = col;
                    }
                }
            }
        }
    }
    // butterfly merge of sorted top-2 lists across the 16 col-lanes (same lg)
#pragma unroll
    for (int off = 1; off < 16; off <<= 1) {
#pragma unroll
        for (int r = 0; r < 16; ++r) {
            const float ov0 = __shfl_xor(sv[r][0], off);
            const int oi0 = __shfl_xor(si[r][0], off);
            const float ov1 = __shfl_xor(sv[r][1], off);
            const int oi1 = __shfl_xor(si[r][1], off);
            if (ov0 < sv[r][0]) {
                const float nv1 = (ov1 < sv[r][0]) ? ov1 : sv[r][0];
                const int ni1 = (ov1 < sv[r][0]) ? oi1 : si[r][0];
                sv[r][0] = ov0; si[r][0] = oi0;
                sv[r][1] = nv1; si[r][1] = ni1;
            } else if (ov0 < sv[r][1]) {
                sv[r][1] = ov0; si[r][1] = oi0;
            }
        }
    }
    if (lc == 0) {
        const int grp = blockIdx.y * 2 + wn;  // 0..7
#pragma unroll
        for (int m = 0; m < 4; ++m)
#pragma unroll
            for (int reg = 0; reg < 4; ++reg) {
                const int r = m * 4 + reg;
                const int t = m0 + wm * 64 + m * 16 + lg * 4 + reg;
                pv[((size_t)grp * 2 + 0) * M_TOK + t] = sv[r][0];
                pi[((size_t)grp * 2 + 0) * M_TOK + t] = si[r][0];
                pv[((size_t)grp * 2 + 1) * M_TOK + t] = sv[r][1];
                pi[((size_t)grp * 2 + 1) * M_TOK + t] = si[r][1];
            }
    }
}

// ---------------- exact fp32 refine over 16 candidates/token -------------
// One wave per token: select top-4 by approx value, compute exact fp32
// distances, argmin with first-index tie-break.
__global__ __launch_bounds__(256) void refine_idx(const float* __restrict__ z,
                                                  const float* __restrict__ cb,
                                                  const float* __restrict__ cnorm,
                                                  const float* __restrict__ pv,
                                                  const int* __restrict__ pi,
                                                  float* __restrict__ idx_f,
                                                  int* __restrict__ idx_i) {
    const int t = blockIdx.x * 4 + (threadIdx.x >> 6);
    const int l = threadIdx.x & 63;
    const float4* zp = reinterpret_cast<const float4*>(z + ((size_t)t << 10));
    float4 zr[4];
#pragma unroll
    for (int j = 0; j < 4; ++j) zr[j] = zp[l + j * 64];

    float v = 3.4e38f;
    int ci = 0x7fffffff;
    if (l < 16) { v = pv[(size_t)l * M_TOK + t]; ci = pi[(size_t)l * M_TOK + t]; }

    float bestd = 3.4e38f;
    int besti = 0x7fffffff;
#pragma unroll
    for (int s = 0; s < 4; ++s) {
        float mv = v;
        int mi = ci;
#pragma unroll
        for (int off = 1; off < 64; off <<= 1) {
            const float o = __shfl_xor(mv, off);
            const int oi2 = __shfl_xor(mi, off);
            if (o < mv || (o == mv && oi2 < mi)) { mv = o; mi = oi2; }
        }
        if (v == mv && ci == mi) v = 3.4e38f;  // consume winner
        const float4* cp = reinterpret_cast<const float4*>(cb + ((size_t)mi << 10));
        float s4 = 0.0f;
#pragma unroll
        for (int j = 0; j < 4; ++j) {
            const float4 c = cp[l + j * 64];
            s4 = fmaf(zr[j].x, c.x, s4);
            s4 = fmaf(zr[j].y, c.y, s4);
            s4 = fmaf(zr[j].z, c.z, s4);
            s4 = fmaf(zr[j].w, c.w, s4);
        }
#pragma unroll
        for (int off = 1; off < 64; off <<= 1) s4 += __shfl_xor(s4, off);
        const float d = cnorm[mi] - 2.0f * s4;
        if (d < bestd || (d == bestd && mi < besti)) { bestd = d; besti = mi; }
    }
    if (l == 0) { idx_f[t] = (float)besti; idx_i[t] = besti; }
}

// ---------------- gather q, in-place z->q, aux loss ----------------------
__global__ __launch_bounds__(256) void quant_aux(const float* __restrict__ cb,
                                                 const int* __restrict__ idx,
                                                 float* __restrict__ zq,
                                                 float* __restrict__ aux) {
    const int t = blockIdx.x;
    const float* c = cb + (size_t)idx[t] * DEMB;
    float* p = zq + (size_t)t * DEMB;
    const int i = threadIdx.x * 4;
    const float4 cv = *reinterpret_cast<const float4*>(c + i);
    const float4 zv = *reinterpret_cast<const float4*>(p + i);
    const float dx = cv.x - zv.x, dy = cv.y - zv.y, dz = cv.z - zv.z, dw = cv.w - zv.w;
    float s = dx * dx + dy * dy + dz * dz + dw * dw;
    *reinterpret_cast<float4*>(p + i) = cv;
    s = block_reduce_sum_256(s);
    if (threadIdx.x == 0) atomicAdd(aux, s * (1.0f / 33554432.0f));
}

extern "C" void kernel_launch(void* const* d_in, const int* in_sizes, int n_in,
                              void* d_out, int out_size, void* d_ws, size_t ws_size,
                              hipStream_t stream) {
    const float* x = (const float*)d_in[0];
    const float* w_in = (const float*)d_in[1];
    const float* b_in = (const float*)d_in[2];
    const float* w_out = (const float*)d_in[3];
    const float* b_out = (const float*)d_in[4];
    const float* cb = (const float*)d_in[5];

    float* out = (float*)d_out;              // [32768, 512]
    float* idx_f = out + IDX_OFF;            // [32768] as float
    float* zq = out + Q_OFF;                 // [32768, 1024]: z, then quantized
    float* aux = out + AUX_OFF;              // scalar

    // z_fp16 lives in the (not-yet-written) out slab: 32768*1024*2B == 64 MiB == out slab size
    _Float16* zf = (_Float16*)d_out;

    char* ws = (char*)d_ws;
    float* cnorm = (float*)ws;                         // 16 KB
    int* idx_i = (int*)(ws + 16384);                   // 128 KB
    float* pv = (float*)(ws + 147456);                 // 16*32768*4 = 2 MB
    int* pi = (int*)(ws + 2244608);                    // 2 MB
    _Float16* cbf = (_Float16*)(ws + 4341760);         // 8 MB

    // 1) codebook norms (+ zero aux)
    cnorm_kernel<<<KC, 256, 0, stream>>>(cb, cnorm, aux);
    // 2) z = x @ w_in^T + b_in  (fp32, into the quantized output slab)
    gemm_nt64<false><<<dim3(DEMB / 64, M_TOK / 64), 256, 0, stream>>>(x, w_in, b_in, zq, nullptr, DIN, DEMB);
    // 3) convert z and codebook to fp16
    to_f16<<<2048, 256, 0, stream>>>(zq, cb, zf, cbf);
    // 4) fp16 MFMA distances + per-group top-2
    dist_topk<<<dim3(M_TOK / 128, 4), 256, 0, stream>>>(zf, cbf, cnorm, pv, pi);
    // 5) exact fp32 refine -> final indices (z still intact in zq)
    refine_idx<<<M_TOK / 4, 256, 0, stream>>>(zq, cb, cnorm, pv, pi, idx_f, idx_i);
    // 6) quantized = codebook[idx] (in place over z), aux = mean((q-z)^2)
    quant_aux<<<M_TOK, 256, 0, stream>>>(cb, idx_i, zq, aux);
    // 7) out = q @ w_out^T + b_out (gathered rows; overwrites z_fp16 region)
    gemm_nt64<true><<<dim3(DIN / 64, M_TOK / 64), 256, 0, stream>>>(cb, w_out, b_out, out, idx_i, DEMB, DIN);
}

// Round 3
// 1023.751 us; speedup vs baseline: 5.5075x; 1.8948x over previous
//
#include <hip/hip_runtime.h>

#define M_TOK 32768
#define DIN   512
#define DEMB  1024
#define KC    4096

#define IDX_OFF ((size_t)M_TOK * DIN)                 // 16777216 floats
#define Q_OFF   (IDX_OFF + M_TOK)                     // 16809984
#define AUX_OFF (Q_OFF + (size_t)M_TOK * DEMB)        // 50364416

typedef _Float16 f16x8 __attribute__((ext_vector_type(8)));
typedef float f32x4 __attribute__((ext_vector_type(4)));

__device__ inline void gload16(const void* g, void* s) {
    __builtin_amdgcn_global_load_lds((const __attribute__((address_space(1))) void*)g,
                                     (__attribute__((address_space(3))) void*)s, 16, 0, 0);
}

// ---------------- block reduction (256 threads = 4 waves) ----------------
__device__ inline float block_reduce_sum_256(float v) {
#pragma unroll
    for (int off = 32; off > 0; off >>= 1) v += __shfl_down(v, off);
    __shared__ float smem[4];
    const int lane = threadIdx.x & 63;
    const int w = threadIdx.x >> 6;
    if (lane == 0) smem[w] = v;
    __syncthreads();
    return smem[0] + smem[1] + smem[2] + smem[3];
}

// ---------------- 0.5*||c||^2 per code; also zero the aux-loss slot ------
__global__ __launch_bounds__(256) void cnorm_kernel(const float* __restrict__ cb,
                                                    float* __restrict__ cn2,
                                                    float* __restrict__ aux) {
    if (blockIdx.x == 0 && threadIdx.x == 0) *aux = 0.0f;
    const float* row = cb + (size_t)blockIdx.x * DEMB;
    const float4 v = *reinterpret_cast<const float4*>(row + threadIdx.x * 4);
    float s = v.x * v.x + v.y * v.y + v.z * v.z + v.w * v.w;
    s = block_reduce_sum_256(s);
    if (threadIdx.x == 0) cn2[blockIdx.x] = 0.5f * s;
}

// ---------------- flat fp32 -> fp16 (8 elems / thread, exact grid) -------
__global__ __launch_bounds__(256) void f32_to_f16(const float* __restrict__ src,
                                                  _Float16* __restrict__ dst) {
    const size_t i = (size_t)blockIdx.x * 256 + threadIdx.x;
    const float4 a = reinterpret_cast<const float4*>(src)[i * 2];
    const float4 b = reinterpret_cast<const float4*>(src)[i * 2 + 1];
    f16x8 h;
    h[0] = (_Float16)a.x; h[1] = (_Float16)a.y; h[2] = (_Float16)a.z; h[3] = (_Float16)a.w;
    h[4] = (_Float16)b.x; h[5] = (_Float16)b.y; h[6] = (_Float16)b.z; h[7] = (_Float16)b.w;
    reinterpret_cast<f16x8*>(dst)[i] = h;
}

// ---------------- fp32 -> fp16 hi/lo split (lo scaled by 2048) -----------
__global__ __launch_bounds__(256) void split_f16(const float* __restrict__ src,
                                                 _Float16* __restrict__ hi,
                                                 _Float16* __restrict__ lo) {
    const size_t i = (size_t)blockIdx.x * 256 + threadIdx.x;
    const float4 a = reinterpret_cast<const float4*>(src)[i * 2];
    const float4 b = reinterpret_cast<const float4*>(src)[i * 2 + 1];
    const float e[8] = {a.x, a.y, a.z, a.w, b.x, b.y, b.z, b.w};
    f16x8 h, l8;
#pragma unroll
    for (int j = 0; j < 8; ++j) {
        const _Float16 hv = (_Float16)e[j];
        h[j] = hv;
        l8[j] = (_Float16)((e[j] - (float)hv) * 2048.0f);
    }
    reinterpret_cast<f16x8*>(hi)[i] = h;
    reinterpret_cast<f16x8*>(lo)[i] = l8;
}

// ---------------- pack codebook into MFMA-fragment-major layout ----------
// block id -> (c16, kk, lane): cbp[((c16*32+kk)*64+l)*8..] = cbf row (c16*16+lc), k=kk*32+lg*8
__global__ __launch_bounds__(256) void pack_cbp(const _Float16* __restrict__ cbf,
                                                _Float16* __restrict__ cbp) {
    const int id = blockIdx.x * 256 + threadIdx.x;   // < 524288
    const int c16 = id >> 11;
    const int rem = id & 2047;
    const int kk = rem >> 6;
    const int l = rem & 63;
    const int lgq = l >> 4, lcq = l & 15;
    const f16x8 v = *reinterpret_cast<const f16x8*>(
        cbf + ((size_t)(c16 * 16 + lcq)) * DEMB + kk * 32 + lgq * 8);
    *reinterpret_cast<f16x8*>(cbp + (size_t)id * 8) = v;
}

// ---------------- z = x @ w_in^T + b (fp16x2-split MFMA, fp32-accurate) ---
// 128x128 tile, 4 waves 2x2, BK=64. A (x) reg-staged + converted hi/lo;
// B (w_in hi/lo, pre-split) via global_load_lds with pre-swizzled source.
__global__ __launch_bounds__(256, 2) void zgemm_split(const float* __restrict__ x,
                                                      const _Float16* __restrict__ wh,
                                                      const _Float16* __restrict__ wl,
                                                      const float* __restrict__ bin,
                                                      float* __restrict__ zq,
                                                      _Float16* __restrict__ zf) {
    extern __shared__ char smem[];
    _Float16* Ah = (_Float16*)smem;        // [128][64] swizzled (16B-chunk ^ row&7)
    _Float16* Al = Ah + 8192;
    _Float16* Bh = Al + 8192;
    _Float16* Bl = Bh + 8192;
    const int t = threadIdx.x;
    const int w = t >> 6, l = t & 63;
    const int wm = w >> 1, wn = w & 1;
    const int lg = l >> 4, lc = l & 15;
    const int m0 = blockIdx.y * 128, n0 = blockIdx.x * 128;

    const int ar = t >> 3;                 // row within 32-row stripe (+i*32)
    const int ach = t & 7;                 // chunk 0..7
    const int aswz = ach ^ (ar & 7);       // i*32 keeps row&7 == ar&7

    f32x4 acc1[4][4] = {};
    f32x4 acc2[4][4] = {};

    for (int kt = 0; kt < 8; ++kt) {
        __syncthreads();
        // B staging: gload16, linear dest, pre-swizzled source chunk
#pragma unroll
        for (int i = 0; i < 4; ++i) {
            const int row = i * 32 + ar;
            const size_t goff = (size_t)(n0 + row) * DIN + kt * 64 + aswz * 8;
            gload16(wh + goff, Bh + (size_t)(i * 256 + t) * 8);
            gload16(wl + goff, Bl + (size_t)(i * 256 + t) * 8);
        }
        // A staging: load fp32, split hi/lo, swizzled ds_write
#pragma unroll
        for (int i = 0; i < 4; ++i) {
            const int row = i * 32 + ar;
            const float* px = x + (size_t)(m0 + row) * DIN + kt * 64 + ach * 8;
            const float4 a = *reinterpret_cast<const float4*>(px);
            const float4 b = *reinterpret_cast<const float4*>(px + 4);
            const float e[8] = {a.x, a.y, a.z, a.w, b.x, b.y, b.z, b.w};
            f16x8 h, l8;
#pragma unroll
            for (int j = 0; j < 8; ++j) {
                const _Float16 hv = (_Float16)e[j];
                h[j] = hv;
                l8[j] = (_Float16)((e[j] - (float)hv) * 2048.0f);
            }
            const int slot = row * 8 + aswz;
            *reinterpret_cast<f16x8*>(Ah + (size_t)slot * 8) = h;
            *reinterpret_cast<f16x8*>(Al + (size_t)slot * 8) = l8;
        }
        __syncthreads();
#pragma unroll
        for (int kk = 0; kk < 2; ++kk) {
            f16x8 ah[4], al8[4], bh[4], bl8[4];
#pragma unroll
            for (int m = 0; m < 4; ++m) {
                const int r = wm * 64 + m * 16 + lc;
                const int c = (kk * 4 + lg) ^ (lc & 7);
                ah[m] = *reinterpret_cast<const f16x8*>(Ah + (size_t)(r * 8 + c) * 8);
                al8[m] = *reinterpret_cast<const f16x8*>(Al + (size_t)(r * 8 + c) * 8);
            }
#pragma unroll
            for (int n = 0; n < 4; ++n) {
                const int r = wn * 64 + n * 16 + lc;
                const int c = (kk * 4 + lg) ^ (lc & 7);
                bh[n] = *reinterpret_cast<const f16x8*>(Bh + (size_t)(r * 8 + c) * 8);
                bl8[n] = *reinterpret_cast<const f16x8*>(Bl + (size_t)(r * 8 + c) * 8);
            }
            __builtin_amdgcn_s_setprio(1);
#pragma unroll
            for (int m = 0; m < 4; ++m)
#pragma unroll
                for (int n = 0; n < 4; ++n) {
                    acc1[m][n] = __builtin_amdgcn_mfma_f32_16x16x32_f16(ah[m], bh[n], acc1[m][n], 0, 0, 0);
                    acc2[m][n] = __builtin_amdgcn_mfma_f32_16x16x32_f16(ah[m], bl8[n], acc2[m][n], 0, 0, 0);
                    acc2[m][n] = __builtin_amdgcn_mfma_f32_16x16x32_f16(al8[m], bh[n], acc2[m][n], 0, 0, 0);
                }
            __builtin_amdgcn_s_setprio(0);
        }
    }
#pragma unroll
    for (int n = 0; n < 4; ++n) {
        const int col = n0 + wn * 64 + n * 16 + lc;
        const float bb = bin[col];
#pragma unroll
        for (int m = 0; m < 4; ++m)
#pragma unroll
            for (int r = 0; r < 4; ++r) {
                const int row = m0 + wm * 64 + m * 16 + lg * 4 + r;
                const float z = acc1[m][n][r] + acc2[m][n][r] * (1.0f / 2048.0f) + bb;
                zq[(size_t)row * DEMB + col] = z;
                zf[(size_t)row * DEMB + col] = (_Float16)z;
            }
    }
}

// ---------------- distance pass: z resident in LDS, cb streamed ----------
// grid 512 blocks x 64 tokens, 8 waves. Wave w sweeps 64-col tiles nt=nt8*8+w
// (mod-8 col classes). B frags loaded coalesced from packed cbp (no LDS, no
// barriers in main loop). Per-wave top-2 -> 16 slots/token.
__global__ __launch_bounds__(512, 2) void dist_topk(const _Float16* __restrict__ zf,
                                                    const _Float16* __restrict__ cbp,
                                                    const float* __restrict__ cn2,
                                                    float* __restrict__ pv,
                                                    int* __restrict__ pi) {
    extern __shared__ _Float16 zt[];   // [64][1024], 16B-chunk ^ (row&15) swizzle
    const int t = threadIdx.x;
    const int w = t >> 6, l = t & 63;
    const int lg = l >> 4, lc = l & 15;
    const int m0 = blockIdx.x * 64;

    {
        const int r0 = t >> 7;          // 0..3 (+i*4)
        const int ch = t & 127;
#pragma unroll
        for (int i = 0; i < 16; ++i) {
            const int row = i * 4 + r0;
            const int sch = (ch & 0x70) | ((ch ^ row) & 15);
            const _Float16* g = zf + (((size_t)(m0 + row)) << 10) + sch * 8;
            gload16(g, zt + ((size_t)(i * 512 + t)) * 8);
        }
    }
    __syncthreads();

    float sv[16][2];
    int si[16][2];
#pragma unroll
    for (int r = 0; r < 16; ++r) {
        sv[r][0] = 3.4e38f; sv[r][1] = 3.4e38f;
        si[r][0] = 0x7fffffff; si[r][1] = 0x7fffffff;
    }

    for (int nt8 = 0; nt8 < 8; ++nt8) {
        const int ntile = nt8 * 8 + w;
        const _Float16* cbb = cbp + ((size_t)ntile * 4) * 32 * 64 * 8;  // c16 = ntile*4
        f32x4 acc[4][4];
#pragma unroll
        for (int m = 0; m < 4; ++m)
#pragma unroll
            for (int n = 0; n < 4; ++n) acc[m][n] = (f32x4){0.f, 0.f, 0.f, 0.f};

        f16x8 bfA[4], bfB[4];
#pragma unroll
        for (int n = 0; n < 4; ++n)
            bfA[n] = *reinterpret_cast<const f16x8*>(cbb + ((size_t)(n * 32) * 64 + l) * 8);

        for (int kk = 0; kk < 32; kk += 2) {
#pragma unroll
            for (int n = 0; n < 4; ++n)
                bfB[n] = *reinterpret_cast<const f16x8*>(cbb + ((size_t)(n * 32 + kk + 1) * 64 + l) * 8);
            f16x8 af[4];
#pragma unroll
            for (int m = 0; m < 4; ++m) {
                const int c = kk * 4 + lg;
                af[m] = *reinterpret_cast<const f16x8*>(
                    zt + (m * 16 + lc) * 1024 + (((c) & 0x70) | ((c ^ lc) & 15)) * 8);
            }
            __builtin_amdgcn_s_setprio(1);
#pragma unroll
            for (int m = 0; m < 4; ++m)
#pragma unroll
                for (int n = 0; n < 4; ++n)
                    acc[m][n] = __builtin_amdgcn_mfma_f32_16x16x32_f16(af[m], bfA[n], acc[m][n], 0, 0, 0);
            __builtin_amdgcn_s_setprio(0);

            const int kkn = (kk + 2) & 31;
#pragma unroll
            for (int n = 0; n < 4; ++n)
                bfA[n] = *reinterpret_cast<const f16x8*>(cbb + ((size_t)(n * 32 + kkn) * 64 + l) * 8);
#pragma unroll
            for (int m = 0; m < 4; ++m) {
                const int c = (kk + 1) * 4 + lg;
                af[m] = *reinterpret_cast<const f16x8*>(
                    zt + (m * 16 + lc) * 1024 + (((c) & 0x70) | ((c ^ lc) & 15)) * 8);
            }
            __builtin_amdgcn_s_setprio(1);
#pragma unroll
            for (int m = 0; m < 4; ++m)
#pragma unroll
                for (int n = 0; n < 4; ++n)
                    acc[m][n] = __builtin_amdgcn_mfma_f32_16x16x32_f16(af[m], bfB[n], acc[m][n], 0, 0, 0);
            __builtin_amdgcn_s_setprio(0);
        }
        // top-2 insert (cols ascend with nt8 and n -> strict < keeps first)
        const int colb = ntile * 64;
#pragma unroll
        for (int n = 0; n < 4; ++n) {
            const int col = colb + n * 16 + lc;
            const float c2 = cn2[col];
#pragma unroll
            for (int m = 0; m < 4; ++m)
#pragma unroll
                for (int rg = 0; rg < 4; ++rg) {
                    const float d = c2 - acc[m][n][rg];
                    const int r = m * 4 + rg;
                    if (d < sv[r][0]) {
                        sv[r][1] = sv[r][0]; si[r][1] = si[r][0];
                        sv[r][0] = d;        si[r][0] = col;
                    } else if (d < sv[r][1]) {
                        sv[r][1] = d; si[r][1] = col;
                    }
                }
        }
    }
    // butterfly merge across the 16 col-lanes (lane bits 0..3)
#pragma unroll
    for (int off = 1; off < 16; off <<= 1) {
#pragma unroll
        for (int r = 0; r < 16; ++r) {
            const float ov0 = __shfl_xor(sv[r][0], off);
            const int oi0 = __shfl_xor(si[r][0], off);
            const float ov1 = __shfl_xor(sv[r][1], off);
            const int oi1 = __shfl_xor(si[r][1], off);
            const bool aw = (sv[r][0] < ov0) || (sv[r][0] == ov0 && si[r][0] <= oi0);
            const float w0v = aw ? sv[r][0] : ov0; const int w0i = aw ? si[r][0] : oi0;
            const float c1v = aw ? sv[r][1] : ov1; const int c1i = aw ? si[r][1] : oi1;
            const float c2v = aw ? ov0 : sv[r][0]; const int c2i = aw ? oi0 : si[r][0];
            const bool bw = (c1v < c2v) || (c1v == c2v && c1i < c2i);
            sv[r][0] = w0v; si[r][0] = w0i;
            sv[r][1] = bw ? c1v : c2v; si[r][1] = bw ? c1i : c2i;
        }
    }
    if (lc == 0) {
#pragma unroll
        for (int m = 0; m < 4; ++m)
#pragma unroll
            for (int rg = 0; rg < 4; ++rg) {
                const int r = m * 4 + rg;
                const int tok = m0 + m * 16 + lg * 4 + rg;
                pv[(size_t)(w * 2 + 0) * M_TOK + tok] = sv[r][0];
                pi[(size_t)(w * 2 + 0) * M_TOK + tok] = si[r][0];
                pv[(size_t)(w * 2 + 1) * M_TOK + tok] = sv[r][1];
                pi[(size_t)(w * 2 + 1) * M_TOK + tok] = si[r][1];
            }
    }
}

// ---------------- exact fp32 refine over 16 candidates/token -------------
__global__ __launch_bounds__(256) void refine_idx(const float* __restrict__ z,
                                                  const float* __restrict__ cb,
                                                  const float* __restrict__ cn2,
                                                  const float* __restrict__ pv,
                                                  const int* __restrict__ pi,
                                                  float* __restrict__ idx_f,
                                                  int* __restrict__ idx_i) {
    const int t = blockIdx.x * 4 + (threadIdx.x >> 6);
    const int l = threadIdx.x & 63;
    const float4* zp = reinterpret_cast<const float4*>(z + ((size_t)t << 10));
    float4 zr[4];
#pragma unroll
    for (int j = 0; j < 4; ++j) zr[j] = zp[l + j * 64];

    float v = 3.4e38f;
    int ci = 0x7fffffff;
    if (l < 16) { v = pv[(size_t)l * M_TOK + t]; ci = pi[(size_t)l * M_TOK + t]; }

    float bestd = 3.4e38f;
    int besti = 0x7fffffff;
#pragma unroll
    for (int s = 0; s < 4; ++s) {
        float mv = v;
        int mi = ci;
#pragma unroll
        for (int off = 1; off < 64; off <<= 1) {
            const float o = __shfl_xor(mv, off);
            const int oi2 = __shfl_xor(mi, off);
            if (o < mv || (o == mv && oi2 < mi)) { mv = o; mi = oi2; }
        }
        if (v == mv && ci == mi) v = 3.4e38f;  // consume winner
        const float4* cp = reinterpret_cast<const float4*>(cb + ((size_t)mi << 10));
        float s4 = 0.0f;
#pragma unroll
        for (int j = 0; j < 4; ++j) {
            const float4 c = cp[l + j * 64];
            s4 = fmaf(zr[j].x, c.x, s4);
            s4 = fmaf(zr[j].y, c.y, s4);
            s4 = fmaf(zr[j].z, c.z, s4);
            s4 = fmaf(zr[j].w, c.w, s4);
        }
#pragma unroll
        for (int off = 1; off < 64; off <<= 1) s4 += __shfl_xor(s4, off);
        const float d = cn2[mi] - s4;
        if (d < bestd || (d == bestd && mi < besti)) { bestd = d; besti = mi; }
    }
    if (l == 0) { idx_f[t] = (float)besti; idx_i[t] = besti; }
}

// ---------------- gather q, in-place z->q, aux loss ----------------------
__global__ __launch_bounds__(256) void quant_aux(const float* __restrict__ cb,
                                                 const int* __restrict__ idx,
                                                 float* __restrict__ zq,
                                                 float* __restrict__ aux) {
    const int t = blockIdx.x;
    const float* c = cb + (size_t)idx[t] * DEMB;
    float* p = zq + (size_t)t * DEMB;
    const int i = threadIdx.x * 4;
    const float4 cv = *reinterpret_cast<const float4*>(c + i);
    const float4 zv = *reinterpret_cast<const float4*>(p + i);
    const float dx = cv.x - zv.x, dy = cv.y - zv.y, dz = cv.z - zv.z, dw = cv.w - zv.w;
    float s = dx * dx + dy * dy + dz * dz + dw * dw;
    *reinterpret_cast<float4*>(p + i) = cv;
    s = block_reduce_sum_256(s);
    if (threadIdx.x == 0) atomicAdd(aux, s * (1.0f / 33554432.0f));
}

// ---------------- out = cb[idx] @ w_out^T + b_out (fp16 MFMA) ------------
// 128x128 tile, 4 waves 2x2, BK=128, gathered A rows via gload16.
__global__ __launch_bounds__(256, 2) void outgemm(const _Float16* __restrict__ cbf,
                                                  const _Float16* __restrict__ wof,
                                                  const float* __restrict__ bout,
                                                  const int* __restrict__ idx,
                                                  float* __restrict__ out) {
    extern __shared__ char smem[];
    _Float16* As = (_Float16*)smem;      // [128][128], 16B-chunk ^ (row&15)
    _Float16* Bs = As + 16384;
    const int t = threadIdx.x;
    const int w = t >> 6, l = t & 63;
    const int wm = w >> 1, wn = w & 1;
    const int lg = l >> 4, lc = l & 15;
    const int m0 = blockIdx.y * 128, n0 = blockIdx.x * 128;

    const int sr = t >> 4;               // + i*16
    const int sch = t & 15;
    const int sswz = sch ^ (sr & 15);    // i*16 keeps row&15

    int arow[8];
#pragma unroll
    for (int i = 0; i < 8; ++i) arow[i] = idx[m0 + i * 16 + sr];

    f32x4 acc[4][4] = {};
    for (int kt = 0; kt < 8; ++kt) {
        __syncthreads();
#pragma unroll
        for (int i = 0; i < 8; ++i) {
            gload16(cbf + (size_t)arow[i] * DEMB + kt * 128 + sswz * 8,
                    As + (size_t)(i * 256 + t) * 8);
            gload16(wof + (size_t)(n0 + i * 16 + sr) * DEMB + kt * 128 + sswz * 8,
                    Bs + (size_t)(i * 256 + t) * 8);
        }
        __syncthreads();
#pragma unroll
        for (int kk = 0; kk < 4; ++kk) {
            f16x8 af[4], bf8[4];
#pragma unroll
            for (int m = 0; m < 4; ++m) {
                const int r = wm * 64 + m * 16 + lc;
                const int c = (kk * 4 + lg) ^ lc;
                af[m] = *reinterpret_cast<const f16x8*>(As + (size_t)(r * 16 + c) * 8);
            }
#pragma unroll
            for (int n = 0; n < 4; ++n) {
                const int r = wn * 64 + n * 16 + lc;
                const int c = (kk * 4 + lg) ^ lc;
                bf8[n] = *reinterpret_cast<const f16x8*>(Bs + (size_t)(r * 16 + c) * 8);
            }
            __builtin_amdgcn_s_setprio(1);
#pragma unroll
            for (int m = 0; m < 4; ++m)
#pragma unroll
                for (int n = 0; n < 4; ++n)
                    acc[m][n] = __builtin_amdgcn_mfma_f32_16x16x32_f16(af[m], bf8[n], acc[m][n], 0, 0, 0);
            __builtin_amdgcn_s_setprio(0);
        }
    }
#pragma unroll
    for (int n = 0; n < 4; ++n) {
        const int col = n0 + wn * 64 + n * 16 + lc;
        const float bb = bout[col];
#pragma unroll
        for (int m = 0; m < 4; ++m)
#pragma unroll
            for (int r = 0; r < 4; ++r) {
                const int row = m0 + wm * 64 + m * 16 + lg * 4 + r;
                out[(size_t)row * DIN + col] = acc[m][n][r] + bb;
            }
    }
}

extern "C" void kernel_launch(void* const* d_in, const int* in_sizes, int n_in,
                              void* d_out, int out_size, void* d_ws, size_t ws_size,
                              hipStream_t stream) {
    const float* x = (const float*)d_in[0];
    const float* w_in = (const float*)d_in[1];
    const float* b_in = (const float*)d_in[2];
    const float* w_out = (const float*)d_in[3];
    const float* b_out = (const float*)d_in[4];
    const float* cb = (const float*)d_in[5];

    float* out = (float*)d_out;              // [32768, 512]
    float* idx_f = out + IDX_OFF;            // [32768] as float
    float* zq = out + Q_OFF;                 // [32768, 1024]: z, then quantized
    float* aux = out + AUX_OFF;              // scalar
    _Float16* zf = (_Float16*)d_out;         // fp16 z, aliases out slab (64 MiB)

    char* ws = (char*)d_ws;
    float* cn2 = (float*)ws;                           // 16 KB
    int* idx_i = (int*)(ws + 16384);                   // 128 KB
    float* pv = (float*)(ws + 147456);                 // 2 MB
    int* pi = (int*)(ws + 2244608);                    // 2 MB
    _Float16* cbf = (_Float16*)(ws + 4341760);         // 8 MB flat fp16 codebook
    _Float16* cbp = (_Float16*)(ws + 12730368);        // 8 MB fragment-packed
    _Float16* wh = (_Float16*)(ws + 21118976);         // 1 MB w_in hi
    _Float16* wl = (_Float16*)(ws + 22167552);         // 1 MB w_in lo (x2048)
    _Float16* wof = (_Float16*)(ws + 23216128);        // 1 MB w_out fp16

    // 1) halved codebook norms (+ zero aux)
    cnorm_kernel<<<KC, 256, 0, stream>>>(cb, cn2, aux);
    // 2) conversions: cb->cbf, w_out->wof, w_in->(wh,wl)
    f32_to_f16<<<2048, 256, 0, stream>>>(cb, cbf);                 // 4M elems
    f32_to_f16<<<256, 256, 0, stream>>>(w_out, wof);               // 512K elems
    split_f16<<<256, 256, 0, stream>>>(w_in, wh, wl);              // 512K elems
    // 3) pack codebook fragments
    pack_cbp<<<2048, 256, 0, stream>>>(cbf, cbp);
    // 4) z = x @ w_in^T + b_in (fp16x2-split MFMA), emits zq fp32 + zf fp16
    zgemm_split<<<dim3(DEMB / 128, M_TOK / 128), 256, 65536, stream>>>(x, wh, wl, b_in, zq, zf);
    // 5) distance sweep: z in LDS, packed cb streamed; 16 top-2 slots/token
    dist_topk<<<M_TOK / 64, 512, 131072, stream>>>(zf, cbp, cn2, pv, pi);
    // 6) exact fp32 refine -> final indices
    refine_idx<<<M_TOK / 4, 256, 0, stream>>>(zq, cb, cn2, pv, pi, idx_f, idx_i);
    // 7) quantized = codebook[idx] (in place over z), aux = mean((q-z)^2)
    quant_aux<<<M_TOK, 256, 0, stream>>>(cb, idx_i, zq, aux);
    // 8) out = cb[idx] @ w_out^T + b_out (fp16 MFMA, overwrites zf region)
    outgemm<<<dim3(DIN / 128, M_TOK / 128), 256, 65536, stream>>>(cbf, wof, b_out, idx_i, out);
}

// Round 4
// 703.696 us; speedup vs baseline: 8.0125x; 1.4548x over previous
//
#include <hip/hip_runtime.h>

#define M_TOK 32768
#define DIN   512
#define DEMB  1024
#define KC    4096

#define IDX_OFF ((size_t)M_TOK * DIN)                 // 16777216 floats
#define Q_OFF   (IDX_OFF + M_TOK)                     // 16809984
#define AUX_OFF (Q_OFF + (size_t)M_TOK * DEMB)        // 50364416

typedef _Float16 f16x8 __attribute__((ext_vector_type(8)));
typedef float f32x4 __attribute__((ext_vector_type(4)));

__device__ inline void gload16(const void* g, void* s) {
    __builtin_amdgcn_global_load_lds((const __attribute__((address_space(1))) void*)g,
                                     (__attribute__((address_space(3))) void*)s, 16, 0, 0);
}

// ---------------- block reduction (256 threads = 4 waves) ----------------
__device__ inline float block_reduce_sum_256(float v) {
#pragma unroll
    for (int off = 32; off > 0; off >>= 1) v += __shfl_down(v, off);
    __shared__ float smem[4];
    const int lane = threadIdx.x & 63;
    const int w = threadIdx.x >> 6;
    if (lane == 0) smem[w] = v;
    __syncthreads();
    return smem[0] + smem[1] + smem[2] + smem[3];
}

// ---------------- 0.5*||c||^2 per code; also zero the aux-loss slot ------
__global__ __launch_bounds__(256) void cnorm_kernel(const float* __restrict__ cb,
                                                    float* __restrict__ cn2,
                                                    float* __restrict__ aux) {
    if (blockIdx.x == 0 && threadIdx.x == 0) *aux = 0.0f;
    const float* row = cb + (size_t)blockIdx.x * DEMB;
    const float4 v = *reinterpret_cast<const float4*>(row + threadIdx.x * 4);
    float s = v.x * v.x + v.y * v.y + v.z * v.z + v.w * v.w;
    s = block_reduce_sum_256(s);
    if (threadIdx.x == 0) cn2[blockIdx.x] = 0.5f * s;
}

// ---------------- flat fp32 -> fp16 (8 elems / thread, exact grid) -------
__global__ __launch_bounds__(256) void f32_to_f16(const float* __restrict__ src,
                                                  _Float16* __restrict__ dst) {
    const size_t i = (size_t)blockIdx.x * 256 + threadIdx.x;
    const float4 a = reinterpret_cast<const float4*>(src)[i * 2];
    const float4 b = reinterpret_cast<const float4*>(src)[i * 2 + 1];
    f16x8 h;
    h[0] = (_Float16)a.x; h[1] = (_Float16)a.y; h[2] = (_Float16)a.z; h[3] = (_Float16)a.w;
    h[4] = (_Float16)b.x; h[5] = (_Float16)b.y; h[6] = (_Float16)b.z; h[7] = (_Float16)b.w;
    reinterpret_cast<f16x8*>(dst)[i] = h;
}

// ---------------- fp32 -> fp16 hi/lo split (lo scaled by 2048) -----------
__global__ __launch_bounds__(256) void split_f16(const float* __restrict__ src,
                                                 _Float16* __restrict__ hi,
                                                 _Float16* __restrict__ lo) {
    const size_t i = (size_t)blockIdx.x * 256 + threadIdx.x;
    const float4 a = reinterpret_cast<const float4*>(src)[i * 2];
    const float4 b = reinterpret_cast<const float4*>(src)[i * 2 + 1];
    const float e[8] = {a.x, a.y, a.z, a.w, b.x, b.y, b.z, b.w};
    f16x8 h, l8;
#pragma unroll
    for (int j = 0; j < 8; ++j) {
        const _Float16 hv = (_Float16)e[j];
        h[j] = hv;
        l8[j] = (_Float16)((e[j] - (float)hv) * 2048.0f);
    }
    reinterpret_cast<f16x8*>(hi)[i] = h;
    reinterpret_cast<f16x8*>(lo)[i] = l8;
}

// ---------------- pack codebook into MFMA-fragment-major layout ----------
__global__ __launch_bounds__(256) void pack_cbp(const _Float16* __restrict__ cbf,
                                                _Float16* __restrict__ cbp) {
    const int id = blockIdx.x * 256 + threadIdx.x;   // < 524288
    const int c16 = id >> 11;
    const int rem = id & 2047;
    const int kk = rem >> 6;
    const int l = rem & 63;
    const int lgq = l >> 4, lcq = l & 15;
    const f16x8 v = *reinterpret_cast<const f16x8*>(
        cbf + ((size_t)(c16 * 16 + lcq)) * DEMB + kk * 32 + lgq * 8);
    *reinterpret_cast<f16x8*>(cbp + (size_t)id * 8) = v;
}

// ---------------- z = x @ w_in^T + b (fp16x2-split MFMA, fp32-accurate) ---
__global__ __launch_bounds__(256, 2) void zgemm_split(const float* __restrict__ x,
                                                      const _Float16* __restrict__ wh,
                                                      const _Float16* __restrict__ wl,
                                                      const float* __restrict__ bin,
                                                      float* __restrict__ zq,
                                                      _Float16* __restrict__ zf) {
    extern __shared__ char smem[];
    _Float16* Ah = (_Float16*)smem;        // [128][64] swizzled (16B-chunk ^ row&7)
    _Float16* Al = Ah + 8192;
    _Float16* Bh = Al + 8192;
    _Float16* Bl = Bh + 8192;
    const int t = threadIdx.x;
    const int w = t >> 6, l = t & 63;
    const int wm = w >> 1, wn = w & 1;
    const int lg = l >> 4, lc = l & 15;
    const int m0 = blockIdx.y * 128, n0 = blockIdx.x * 128;

    const int ar = t >> 3;
    const int ach = t & 7;
    const int aswz = ach ^ (ar & 7);

    f32x4 acc1[4][4] = {};
    f32x4 acc2[4][4] = {};

    for (int kt = 0; kt < 8; ++kt) {
        __syncthreads();
#pragma unroll
        for (int i = 0; i < 4; ++i) {
            const int row = i * 32 + ar;
            const size_t goff = (size_t)(n0 + row) * DIN + kt * 64 + aswz * 8;
            gload16(wh + goff, Bh + (size_t)(i * 256 + t) * 8);
            gload16(wl + goff, Bl + (size_t)(i * 256 + t) * 8);
        }
#pragma unroll
        for (int i = 0; i < 4; ++i) {
            const int row = i * 32 + ar;
            const float* px = x + (size_t)(m0 + row) * DIN + kt * 64 + ach * 8;
            const float4 a = *reinterpret_cast<const float4*>(px);
            const float4 b = *reinterpret_cast<const float4*>(px + 4);
            const float e[8] = {a.x, a.y, a.z, a.w, b.x, b.y, b.z, b.w};
            f16x8 h, l8;
#pragma unroll
            for (int j = 0; j < 8; ++j) {
                const _Float16 hv = (_Float16)e[j];
                h[j] = hv;
                l8[j] = (_Float16)((e[j] - (float)hv) * 2048.0f);
            }
            const int slot = row * 8 + aswz;
            *reinterpret_cast<f16x8*>(Ah + (size_t)slot * 8) = h;
            *reinterpret_cast<f16x8*>(Al + (size_t)slot * 8) = l8;
        }
        __syncthreads();
#pragma unroll
        for (int kk = 0; kk < 2; ++kk) {
            f16x8 ah[4], al8[4], bh[4], bl8[4];
#pragma unroll
            for (int m = 0; m < 4; ++m) {
                const int r = wm * 64 + m * 16 + lc;
                const int c = (kk * 4 + lg) ^ (lc & 7);
                ah[m] = *reinterpret_cast<const f16x8*>(Ah + (size_t)(r * 8 + c) * 8);
                al8[m] = *reinterpret_cast<const f16x8*>(Al + (size_t)(r * 8 + c) * 8);
            }
#pragma unroll
            for (int n = 0; n < 4; ++n) {
                const int r = wn * 64 + n * 16 + lc;
                const int c = (kk * 4 + lg) ^ (lc & 7);
                bh[n] = *reinterpret_cast<const f16x8*>(Bh + (size_t)(r * 8 + c) * 8);
                bl8[n] = *reinterpret_cast<const f16x8*>(Bl + (size_t)(r * 8 + c) * 8);
            }
            __builtin_amdgcn_s_setprio(1);
#pragma unroll
            for (int m = 0; m < 4; ++m)
#pragma unroll
                for (int n = 0; n < 4; ++n) {
                    acc1[m][n] = __builtin_amdgcn_mfma_f32_16x16x32_f16(ah[m], bh[n], acc1[m][n], 0, 0, 0);
                    acc2[m][n] = __builtin_amdgcn_mfma_f32_16x16x32_f16(ah[m], bl8[n], acc2[m][n], 0, 0, 0);
                    acc2[m][n] = __builtin_amdgcn_mfma_f32_16x16x32_f16(al8[m], bh[n], acc2[m][n], 0, 0, 0);
                }
            __builtin_amdgcn_s_setprio(0);
        }
    }
#pragma unroll
    for (int n = 0; n < 4; ++n) {
        const int col = n0 + wn * 64 + n * 16 + lc;
        const float bb = bin[col];
#pragma unroll
        for (int m = 0; m < 4; ++m)
#pragma unroll
            for (int r = 0; r < 4; ++r) {
                const int row = m0 + wm * 64 + m * 16 + lg * 4 + r;
                const float z = acc1[m][n][r] + acc2[m][n][r] * (1.0f / 2048.0f) + bb;
                zq[(size_t)row * DEMB + col] = z;
                zf[(size_t)row * DEMB + col] = (_Float16)z;
            }
    }
}

// ---------------- distance pass: z resident in LDS, cb streamed ----------
__global__ __launch_bounds__(512, 2) void dist_topk(const _Float16* __restrict__ zf,
                                                    const _Float16* __restrict__ cbp,
                                                    const float* __restrict__ cn2,
                                                    float* __restrict__ pv,
                                                    int* __restrict__ pi) {
    extern __shared__ _Float16 zt[];   // [64][1024], 16B-chunk ^ (row&15) swizzle
    const int t = threadIdx.x;
    const int w = t >> 6, l = t & 63;
    const int lg = l >> 4, lc = l & 15;
    const int m0 = blockIdx.x * 64;

    {
        const int r0 = t >> 7;
        const int ch = t & 127;
#pragma unroll
        for (int i = 0; i < 16; ++i) {
            const int row = i * 4 + r0;
            const int sch = (ch & 0x70) | ((ch ^ row) & 15);
            const _Float16* g = zf + (((size_t)(m0 + row)) << 10) + sch * 8;
            gload16(g, zt + ((size_t)(i * 512 + t)) * 8);
        }
    }
    __syncthreads();

    float sv[16][2];
    int si[16][2];
#pragma unroll
    for (int r = 0; r < 16; ++r) {
        sv[r][0] = 3.4e38f; sv[r][1] = 3.4e38f;
        si[r][0] = 0x7fffffff; si[r][1] = 0x7fffffff;
    }

    for (int nt8 = 0; nt8 < 8; ++nt8) {
        const int ntile = nt8 * 8 + w;
        const _Float16* cbb = cbp + ((size_t)ntile * 4) * 32 * 64 * 8;
        f32x4 acc[4][4];
#pragma unroll
        for (int m = 0; m < 4; ++m)
#pragma unroll
            for (int n = 0; n < 4; ++n) acc[m][n] = (f32x4){0.f, 0.f, 0.f, 0.f};

        f16x8 bfA[4], bfB[4];
#pragma unroll
        for (int n = 0; n < 4; ++n)
            bfA[n] = *reinterpret_cast<const f16x8*>(cbb + ((size_t)(n * 32) * 64 + l) * 8);

        for (int kk = 0; kk < 32; kk += 2) {
#pragma unroll
            for (int n = 0; n < 4; ++n)
                bfB[n] = *reinterpret_cast<const f16x8*>(cbb + ((size_t)(n * 32 + kk + 1) * 64 + l) * 8);
            f16x8 af[4];
#pragma unroll
            for (int m = 0; m < 4; ++m) {
                const int c = kk * 4 + lg;
                af[m] = *reinterpret_cast<const f16x8*>(
                    zt + (m * 16 + lc) * 1024 + (((c) & 0x70) | ((c ^ lc) & 15)) * 8);
            }
            __builtin_amdgcn_s_setprio(1);
#pragma unroll
            for (int m = 0; m < 4; ++m)
#pragma unroll
                for (int n = 0; n < 4; ++n)
                    acc[m][n] = __builtin_amdgcn_mfma_f32_16x16x32_f16(af[m], bfA[n], acc[m][n], 0, 0, 0);
            __builtin_amdgcn_s_setprio(0);

            const int kkn = (kk + 2) & 31;
#pragma unroll
            for (int n = 0; n < 4; ++n)
                bfA[n] = *reinterpret_cast<const f16x8*>(cbb + ((size_t)(n * 32 + kkn) * 64 + l) * 8);
#pragma unroll
            for (int m = 0; m < 4; ++m) {
                const int c = (kk + 1) * 4 + lg;
                af[m] = *reinterpret_cast<const f16x8*>(
                    zt + (m * 16 + lc) * 1024 + (((c) & 0x70) | ((c ^ lc) & 15)) * 8);
            }
            __builtin_amdgcn_s_setprio(1);
#pragma unroll
            for (int m = 0; m < 4; ++m)
#pragma unroll
                for (int n = 0; n < 4; ++n)
                    acc[m][n] = __builtin_amdgcn_mfma_f32_16x16x32_f16(af[m], bfB[n], acc[m][n], 0, 0, 0);
            __builtin_amdgcn_s_setprio(0);
        }
        const int colb = ntile * 64;
#pragma unroll
        for (int n = 0; n < 4; ++n) {
            const int col = colb + n * 16 + lc;
            const float c2 = cn2[col];
#pragma unroll
            for (int m = 0; m < 4; ++m)
#pragma unroll
                for (int rg = 0; rg < 4; ++rg) {
                    const float d = c2 - acc[m][n][rg];
                    const int r = m * 4 + rg;
                    if (d < sv[r][0]) {
                        sv[r][1] = sv[r][0]; si[r][1] = si[r][0];
                        sv[r][0] = d;        si[r][0] = col;
                    } else if (d < sv[r][1]) {
                        sv[r][1] = d; si[r][1] = col;
                    }
                }
        }
    }
#pragma unroll
    for (int off = 1; off < 16; off <<= 1) {
#pragma unroll
        for (int r = 0; r < 16; ++r) {
            const float ov0 = __shfl_xor(sv[r][0], off);
            const int oi0 = __shfl_xor(si[r][0], off);
            const float ov1 = __shfl_xor(sv[r][1], off);
            const int oi1 = __shfl_xor(si[r][1], off);
            const bool aw = (sv[r][0] < ov0) || (sv[r][0] == ov0 && si[r][0] <= oi0);
            const float w0v = aw ? sv[r][0] : ov0; const int w0i = aw ? si[r][0] : oi0;
            const float c1v = aw ? sv[r][1] : ov1; const int c1i = aw ? si[r][1] : oi1;
            const float c2v = aw ? ov0 : sv[r][0]; const int c2i = aw ? oi0 : si[r][0];
            const bool bw = (c1v < c2v) || (c1v == c2v && c1i < c2i);
            sv[r][0] = w0v; si[r][0] = w0i;
            sv[r][1] = bw ? c1v : c2v; si[r][1] = bw ? c1i : c2i;
        }
    }
    if (lc == 0) {
#pragma unroll
        for (int m = 0; m < 4; ++m)
#pragma unroll
            for (int rg = 0; rg < 4; ++rg) {
                const int r = m * 4 + rg;
                const int tok = m0 + m * 16 + lg * 4 + rg;
                pv[(size_t)(w * 2 + 0) * M_TOK + tok] = sv[r][0];
                pi[(size_t)(w * 2 + 0) * M_TOK + tok] = si[r][0];
                pv[(size_t)(w * 2 + 1) * M_TOK + tok] = sv[r][1];
                pi[(size_t)(w * 2 + 1) * M_TOK + tok] = si[r][1];
            }
    }
}

// ---------------- exact fp32 refine + aux-loss accumulation --------------
// ||q-z||^2 = 2*(cn2[best] - s4_best) + ||z||^2  (all fp32-exact terms)
__global__ __launch_bounds__(256) void refine_idx(const float* __restrict__ z,
                                                  const float* __restrict__ cb,
                                                  const float* __restrict__ cn2,
                                                  const float* __restrict__ pv,
                                                  const int* __restrict__ pi,
                                                  float* __restrict__ idx_f,
                                                  int* __restrict__ idx_i,
                                                  float* __restrict__ aux) {
    const int wv = threadIdx.x >> 6;
    const int t = blockIdx.x * 4 + wv;
    const int l = threadIdx.x & 63;
    const float4* zp = reinterpret_cast<const float4*>(z + ((size_t)t << 10));
    float4 zr[4];
#pragma unroll
    for (int j = 0; j < 4; ++j) zr[j] = zp[l + j * 64];

    // ||z||^2
    float zn = 0.0f;
#pragma unroll
    for (int j = 0; j < 4; ++j) {
        zn = fmaf(zr[j].x, zr[j].x, zn);
        zn = fmaf(zr[j].y, zr[j].y, zn);
        zn = fmaf(zr[j].z, zr[j].z, zn);
        zn = fmaf(zr[j].w, zr[j].w, zn);
    }
#pragma unroll
    for (int off = 1; off < 64; off <<= 1) zn += __shfl_xor(zn, off);

    float v = 3.4e38f;
    int ci = 0x7fffffff;
    if (l < 16) { v = pv[(size_t)l * M_TOK + t]; ci = pi[(size_t)l * M_TOK + t]; }

    float bestd = 3.4e38f;
    int besti = 0x7fffffff;
#pragma unroll
    for (int s = 0; s < 4; ++s) {
        float mv = v;
        int mi = ci;
#pragma unroll
        for (int off = 1; off < 64; off <<= 1) {
            const float o = __shfl_xor(mv, off);
            const int oi2 = __shfl_xor(mi, off);
            if (o < mv || (o == mv && oi2 < mi)) { mv = o; mi = oi2; }
        }
        if (v == mv && ci == mi) v = 3.4e38f;  // consume winner
        const float4* cp = reinterpret_cast<const float4*>(cb + ((size_t)mi << 10));
        float s4 = 0.0f;
#pragma unroll
        for (int j = 0; j < 4; ++j) {
            const float4 c = cp[l + j * 64];
            s4 = fmaf(zr[j].x, c.x, s4);
            s4 = fmaf(zr[j].y, c.y, s4);
            s4 = fmaf(zr[j].z, c.z, s4);
            s4 = fmaf(zr[j].w, c.w, s4);
        }
#pragma unroll
        for (int off = 1; off < 64; off <<= 1) s4 += __shfl_xor(s4, off);
        const float d = cn2[mi] - s4;
        if (d < bestd || (d == bestd && mi < besti)) { bestd = d; besti = mi; }
    }
    __shared__ float dsum[4];
    if (l == 0) {
        idx_f[t] = (float)besti;
        idx_i[t] = besti;
        dsum[wv] = 2.0f * bestd + zn;   // ||q - z||^2 for this token
    }
    __syncthreads();
    if (threadIdx.x == 0)
        atomicAdd(aux, (dsum[0] + dsum[1] + dsum[2] + dsum[3]) * (1.0f / 33554432.0f));
}

// ---------------- quantized = codebook[idx] (pure gather-write) ----------
__global__ __launch_bounds__(256) void gather_q(const float* __restrict__ cb,
                                                const int* __restrict__ idx,
                                                float* __restrict__ zq) {
    const int b = blockIdx.x;  // 2048 blocks x 16 tokens
    int cidx[16];
#pragma unroll
    for (int tt = 0; tt < 16; ++tt) cidx[tt] = idx[b * 16 + tt];
#pragma unroll
    for (int tt = 0; tt < 16; ++tt) {
        const float4 v = reinterpret_cast<const float4*>(cb + ((size_t)cidx[tt] << 10))[threadIdx.x];
        reinterpret_cast<float4*>(zq + ((size_t)(b * 16 + tt) << 10))[threadIdx.x] = v;
    }
}

// ---------------- out = cb[idx] @ w_out^T + b_out (fp16 MFMA) ------------
__global__ __launch_bounds__(256, 2) void outgemm(const _Float16* __restrict__ cbf,
                                                  const _Float16* __restrict__ wof,
                                                  const float* __restrict__ bout,
                                                  const int* __restrict__ idx,
                                                  float* __restrict__ out) {
    extern __shared__ char smem[];
    _Float16* As = (_Float16*)smem;      // [128][128], 16B-chunk ^ (row&15)
    _Float16* Bs = As + 16384;
    const int t = threadIdx.x;
    const int w = t >> 6, l = t & 63;
    const int wm = w >> 1, wn = w & 1;
    const int lg = l >> 4, lc = l & 15;
    const int m0 = blockIdx.y * 128, n0 = blockIdx.x * 128;

    const int sr = t >> 4;
    const int sch = t & 15;
    const int sswz = sch ^ (sr & 15);

    int arow[8];
#pragma unroll
    for (int i = 0; i < 8; ++i) arow[i] = idx[m0 + i * 16 + sr];

    f32x4 acc[4][4] = {};
    for (int kt = 0; kt < 8; ++kt) {
        __syncthreads();
#pragma unroll
        for (int i = 0; i < 8; ++i) {
            gload16(cbf + (size_t)arow[i] * DEMB + kt * 128 + sswz * 8,
                    As + (size_t)(i * 256 + t) * 8);
            gload16(wof + (size_t)(n0 + i * 16 + sr) * DEMB + kt * 128 + sswz * 8,
                    Bs + (size_t)(i * 256 + t) * 8);
        }
        __syncthreads();
#pragma unroll
        for (int kk = 0; kk < 4; ++kk) {
            f16x8 af[4], bf8[4];
#pragma unroll
            for (int m = 0; m < 4; ++m) {
                const int r = wm * 64 + m * 16 + lc;
                const int c = (kk * 4 + lg) ^ lc;
                af[m] = *reinterpret_cast<const f16x8*>(As + (size_t)(r * 16 + c) * 8);
            }
#pragma unroll
            for (int n = 0; n < 4; ++n) {
                const int r = wn * 64 + n * 16 + lc;
                const int c = (kk * 4 + lg) ^ lc;
                bf8[n] = *reinterpret_cast<const f16x8*>(Bs + (size_t)(r * 16 + c) * 8);
            }
            __builtin_amdgcn_s_setprio(1);
#pragma unroll
            for (int m = 0; m < 4; ++m)
#pragma unroll
                for (int n = 0; n < 4; ++n)
                    acc[m][n] = __builtin_amdgcn_mfma_f32_16x16x32_f16(af[m], bf8[n], acc[m][n], 0, 0, 0);
            __builtin_amdgcn_s_setprio(0);
        }
    }
#pragma unroll
    for (int n = 0; n < 4; ++n) {
        const int col = n0 + wn * 64 + n * 16 + lc;
        const float bb = bout[col];
#pragma unroll
        for (int m = 0; m < 4; ++m)
#pragma unroll
            for (int r = 0; r < 4; ++r) {
                const int row = m0 + wm * 64 + m * 16 + lg * 4 + r;
                out[(size_t)row * DIN + col] = acc[m][n][r] + bb;
            }
    }
}

extern "C" void kernel_launch(void* const* d_in, const int* in_sizes, int n_in,
                              void* d_out, int out_size, void* d_ws, size_t ws_size,
                              hipStream_t stream) {
    const float* x = (const float*)d_in[0];
    const float* w_in = (const float*)d_in[1];
    const float* b_in = (const float*)d_in[2];
    const float* w_out = (const float*)d_in[3];
    const float* b_out = (const float*)d_in[4];
    const float* cb = (const float*)d_in[5];

    float* out = (float*)d_out;              // [32768, 512]
    float* idx_f = out + IDX_OFF;            // [32768] as float
    float* zq = out + Q_OFF;                 // [32768, 1024]: z, then quantized
    float* aux = out + AUX_OFF;              // scalar
    _Float16* zf = (_Float16*)d_out;         // fp16 z, aliases out slab (64 MiB)

    char* ws = (char*)d_ws;
    float* cn2 = (float*)ws;                           // 16 KB
    int* idx_i = (int*)(ws + 16384);                   // 128 KB
    float* pv = (float*)(ws + 147456);                 // 2 MB
    int* pi = (int*)(ws + 2244608);                    // 2 MB
    _Float16* cbf = (_Float16*)(ws + 4341760);         // 8 MB flat fp16 codebook
    _Float16* cbp = (_Float16*)(ws + 12730368);        // 8 MB fragment-packed
    _Float16* wh = (_Float16*)(ws + 21118976);         // 1 MB w_in hi
    _Float16* wl = (_Float16*)(ws + 22167552);         // 1 MB w_in lo (x2048)
    _Float16* wof = (_Float16*)(ws + 23216128);        // 1 MB w_out fp16

    // 1) halved codebook norms (+ zero aux)
    cnorm_kernel<<<KC, 256, 0, stream>>>(cb, cn2, aux);
    // 2) conversions: cb->cbf, w_out->wof, w_in->(wh,wl)
    f32_to_f16<<<2048, 256, 0, stream>>>(cb, cbf);
    f32_to_f16<<<256, 256, 0, stream>>>(w_out, wof);
    split_f16<<<256, 256, 0, stream>>>(w_in, wh, wl);
    // 3) pack codebook fragments
    pack_cbp<<<2048, 256, 0, stream>>>(cbf, cbp);
    // 4) z = x @ w_in^T + b_in (fp16x2-split MFMA), emits zq fp32 + zf fp16
    zgemm_split<<<dim3(DEMB / 128, M_TOK / 128), 256, 65536, stream>>>(x, wh, wl, b_in, zq, zf);
    // 5) distance sweep: z in LDS, packed cb streamed; 16 top-2 slots/token
    dist_topk<<<M_TOK / 64, 512, 131072, stream>>>(zf, cbp, cn2, pv, pi);
    // 6) exact fp32 refine -> final indices + aux loss (z still intact in zq)
    refine_idx<<<M_TOK / 4, 256, 0, stream>>>(zq, cb, cn2, pv, pi, idx_f, idx_i, aux);
    // 7) quantized = codebook[idx] (pure gather-write over z)
    gather_q<<<M_TOK / 16, 256, 0, stream>>>(cb, idx_i, zq);
    // 8) out = cb[idx] @ w_out^T + b_out (fp16 MFMA, overwrites zf region)
    outgemm<<<dim3(DIN / 128, M_TOK / 128), 256, 65536, stream>>>(cbf, wof, b_out, idx_i, out);
}